// Round 3
// baseline (266.261 us; speedup 1.0000x reference)
//
#include <hip/hip_runtime.h>
#include <hip/hip_bf16.h>

// NonLocalBlock B=4,C=256,H=W=64 (N=4096) — round 3.
//  prep_x: x fp32 [b][c][n] -> xT bf16 [b][n][c]   (global transpose)
//  qkv   : LDS-free streaming MFMA; weights cvt in-register from fp32 L2
//  attn  : producer(S)/consumer(O) wave-specialized flash loop, 1 barrier/step
//  proj  : LDS-free streaming MFMA + residual
// ws = xT | QT(=ATT out, per-tile self-overwrite is block-local) | KT | V = 32 MiB.

typedef __attribute__((ext_vector_type(4))) short s16x4;
typedef __attribute__((ext_vector_type(8))) short s16x8;
typedef __attribute__((ext_vector_type(16))) float f32x16;

#define MFMA32(a, b, c) __builtin_amdgcn_mfma_f32_32x32x16_bf16((a), (b), (c), 0, 0, 0)

constexpr int Cc = 256;
constexpr int Nn = 4096;

__device__ inline short f2bf(float f) {
    unsigned int u = __builtin_bit_cast(unsigned int, f);
    u = (u + 0x7fffu + ((u >> 16) & 1u)) >> 16;   // RNE
    return (short)u;
}

// 32x32x16 bf16 MFMA layouts (m74/m101-verified C/D; A/B symmetric k-map):
//   A[m=lane&31][k=(lane>>5)*8+j]   B[k=(lane>>5)*8+j][n=lane&31]
//   C/D: col=lane&31, row=(r&3)+8*(r>>2)+4*(lane>>5)

// ---------------------------------------------------------------- prep
__global__ __launch_bounds__(256, 4) void prep_x(
    const float* __restrict__ x, short* __restrict__ xT)
{
    const int nt = blockIdx.x, ct = blockIdx.y, b = blockIdx.z;
    const int n0 = nt * 64, c0 = ct * 64;
    __shared__ short T[64][72];                 // [n][c]
    const int t = threadIdx.x;
    const float* xb = x + (size_t)b * Cc * Nn;
    #pragma unroll
    for (int r = 0; r < 16; ++r) {
        int c = r * 4 + (t >> 6), n = t & 63;   // coalesced on n
        T[n][c] = f2bf(xb[(size_t)(c0 + c) * Nn + n0 + n]);
    }
    __syncthreads();
    short* o = xT + (size_t)b * Nn * Cc;
    #pragma unroll
    for (int r = 0; r < 4; ++r) {
        int n = r * 16 + (t >> 4), c4 = (t & 15) * 4;
        *(s16x4*)&o[(size_t)(n0 + n) * Cc + c0 + c4] = *(const s16x4*)&T[n][c4];
    }
}

// ---------------------------------------------------------------- qkv
__global__ __launch_bounds__(256, 3) void qkv_kernel(
    const short* __restrict__ xT,
    const float* __restrict__ wq, const float* __restrict__ bq,
    const float* __restrict__ wk, const float* __restrict__ bk,
    const float* __restrict__ wv, const float* __restrict__ bv,
    short* __restrict__ QT, short* __restrict__ KT, short* __restrict__ V)
{
    const int nt = blockIdx.x, b = blockIdx.y, mat = blockIdx.z;
    const int n0 = nt * 64;
    const float* w    = (mat == 0) ? wq : (mat == 1) ? wk : wv;
    const float* bias = (mat == 0) ? bq : (mat == 1) ? bk : bv;
    const int t = threadIdx.x, lane = t & 63, wid = t >> 6, h = lane >> 5, l31 = lane & 31;
    const short* A = xT + (size_t)b * Nn * Cc;

    f32x16 acc[4];
    #pragma unroll
    for (int s = 0; s < 4; ++s)
        #pragma unroll
        for (int r = 0; r < 16; ++r) acc[s][r] = 0.f;

    if (mat < 2) {
        // D[n][o] = sum_c xT[n][c] w[o][c]
        const int mw = wid & 1, nwb = (wid >> 1) * 4;
        const short* arow = A + (size_t)(n0 + mw*32 + l31) * Cc + h*8;
        #pragma unroll 4
        for (int kk = 0; kk < 16; ++kk) {       // cbase = kk*16
            s16x8 a = *(const s16x8*)(arow + kk*16);
            #pragma unroll
            for (int s = 0; s < 4; ++s) {
                const float* wr = w + (size_t)((nwb + s)*32 + l31) * Cc + kk*16 + h*8;
                float4 lo = *(const float4*)wr, hi = *(const float4*)(wr + 4);
                s16x8 bb = { f2bf(lo.x), f2bf(lo.y), f2bf(lo.z), f2bf(lo.w),
                             f2bf(hi.x), f2bf(hi.y), f2bf(hi.z), f2bf(hi.w) };
                acc[s] = MFMA32(a, bb, acc[s]);
            }
        }
        short* dst = ((mat == 0) ? QT : KT) + (size_t)b * Nn * Cc;
        #pragma unroll
        for (int s = 0; s < 4; ++s) {
            int o = (nwb + s)*32 + l31;
            float bia = bias[o];
            #pragma unroll
            for (int r = 0; r < 16; ++r) {
                int n = mw*32 + (r & 3) + 8*(r >> 2) + 4*h;
                dst[(size_t)(n0 + n) * Cc + o] = f2bf(acc[s][r] + bia);
            }
        }
    } else {
        // D[o][n] = sum_c w[o][c] xT[n][c]
        #pragma unroll 4
        for (int kk = 0; kk < 16; ++kk) {
            const float* w0 = w + (size_t)((wid*2 + 0)*32 + l31) * Cc + kk*16 + h*8;
            const float* w1 = w + (size_t)((wid*2 + 1)*32 + l31) * Cc + kk*16 + h*8;
            float4 l0 = *(const float4*)w0, h0 = *(const float4*)(w0 + 4);
            float4 l1 = *(const float4*)w1, h1 = *(const float4*)(w1 + 4);
            s16x8 a0 = { f2bf(l0.x), f2bf(l0.y), f2bf(l0.z), f2bf(l0.w),
                         f2bf(h0.x), f2bf(h0.y), f2bf(h0.z), f2bf(h0.w) };
            s16x8 a1 = { f2bf(l1.x), f2bf(l1.y), f2bf(l1.z), f2bf(l1.w),
                         f2bf(h1.x), f2bf(h1.y), f2bf(h1.z), f2bf(h1.w) };
            s16x8 b0 = *(const s16x8*)&A[(size_t)(n0 +  0 + l31) * Cc + kk*16 + h*8];
            s16x8 b1 = *(const s16x8*)&A[(size_t)(n0 + 32 + l31) * Cc + kk*16 + h*8];
            acc[0] = MFMA32(a0, b0, acc[0]);
            acc[1] = MFMA32(a0, b1, acc[1]);
            acc[2] = MFMA32(a1, b0, acc[2]);
            acc[3] = MFMA32(a1, b1, acc[3]);
        }
        short* dst = V + (size_t)b * Cc * Nn;
        #pragma unroll
        for (int sub = 0; sub < 4; ++sub) {
            int mc = sub >> 1, nc = sub & 1;
            int nloc = nc*32 + l31;
            #pragma unroll
            for (int r = 0; r < 16; ++r) {
                int o = (wid*2 + mc)*32 + (r & 3) + 8*(r >> 2) + 4*h;
                dst[(size_t)o * Nn + n0 + nloc] = f2bf(acc[sub][r] + bias[o]);
            }
        }
    }
}

// ---------------------------------------------------------------- attn
// 512 threads: waves 0-3 produce P (QK+exp), waves 4-7 consume (PV).
// LDS: Ks dbuf 67584 + Ps dbuf 18432 + lpart/linv ~768 = ~87 KB, 1 block/CU.
__global__ __launch_bounds__(512, 2) void attn_kernel(
    const short* __restrict__ QTg, const short* __restrict__ KTg,
    const short* __restrict__ Vg, short* __restrict__ ATT)
{
    const int bid = blockIdx.x;
    const int b  = (bid & 7) >> 1;              // batch per XCD pair
    const int qt = ((bid >> 3) << 1) | (bid & 1);
    const int i0 = qt * 64;

    const int t = threadIdx.x, lane = t & 63, wid = t >> 6, h = lane >> 5, l31 = lane & 31;

    __shared__ alignas(16) short Ks[2][64][264];
    __shared__ alignas(16) short Ps[2][64][72];
    __shared__ float lpart[2][64];
    __shared__ float linv[64];

    if (t < 128) lpart[t >> 6][t & 63] = 0.f;

    const short* Qb = QTg + (size_t)b * Nn * Cc;
    const short* Kb = KTg + (size_t)b * Nn * Cc;
    const short* Vb = Vg  + (size_t)b * Cc * Nn;

    const float SC = 0.09016844005f;            // C^-0.5 * log2(e)
    f32x16 oacc[4];                             // O-group only

    if (wid < 4) {
        // ---------------- producer: S = K Q^T, exp, P
        const int w4 = wid, mj = w4 >> 1, ni = w4 & 1;
        const int sid = w4 * 64 + lane;         // 0..255 staging id
        const int krow = sid >> 5, kcol = (sid & 31) * 8;

        s16x8 qf[16];
        {
            const short* qrow = Qb + (size_t)(i0 + ni*32 + l31) * Cc + h*8;
            #pragma unroll
            for (int kc = 0; kc < 16; ++kc) qf[kc] = *(const s16x8*)(qrow + kc*16);
        }
        s16x8 kpre[8];
        #pragma unroll
        for (int li = 0; li < 8; ++li)
            kpre[li] = *(const s16x8*)&Kb[(size_t)(li*8 + krow) * Cc + kcol];

        for (int tt = 0; tt < 66; ++tt) {
            if (tt < 64) {
                #pragma unroll
                for (int li = 0; li < 8; ++li)
                    *(s16x8*)&Ks[tt & 1][li*8 + krow][kcol] = kpre[li];
                if (tt + 1 < 64) {
                    #pragma unroll
                    for (int li = 0; li < 8; ++li)
                        kpre[li] = *(const s16x8*)&Kb[(size_t)((tt+1)*64 + li*8 + krow) * Cc + kcol];
                }
            }
            if (tt >= 1 && tt <= 64) {
                const int jt = tt - 1, kb = jt & 1;
                f32x16 s0, s1;
                #pragma unroll
                for (int r = 0; r < 16; ++r) { s0[r] = 0.f; s1[r] = 0.f; }
                #pragma unroll
                for (int kc = 0; kc < 8; ++kc) {
                    s16x8 a0 = *(const s16x8*)&Ks[kb][mj*32 + l31][(2*kc + 0)*16 + h*8];
                    s16x8 a1 = *(const s16x8*)&Ks[kb][mj*32 + l31][(2*kc + 1)*16 + h*8];
                    s0 = MFMA32(a0, qf[2*kc + 0], s0);
                    s1 = MFMA32(a1, qf[2*kc + 1], s1);
                }
                float ps[16], lsum = 0.f;
                #pragma unroll
                for (int r = 0; r < 16; ++r) {
                    float e = exp2f((s0[r] + s1[r]) * SC);
                    ps[r] = e; lsum += e;
                }
                lsum += __shfl_xor(lsum, 32);
                if (h == 0) lpart[mj][ni*32 + l31] += lsum;
                const int ip = ni*32 + l31;
                #pragma unroll
                for (int g = 0; g < 4; ++g) {
                    s16x4 pk = { f2bf(ps[4*g+0]), f2bf(ps[4*g+1]),
                                 f2bf(ps[4*g+2]), f2bf(ps[4*g+3]) };
                    *(s16x4*)&Ps[kb][ip][mj*32 + g*8 + 4*h] = pk;
                }
            }
            __syncthreads();
        }
    } else {
        // ---------------- consumer: O^T[c][i] += V[c][j] P[i][j]
        const int w2 = wid - 4;
        #pragma unroll
        for (int s = 0; s < 4; ++s)
            #pragma unroll
            for (int r = 0; r < 16; ++r) oacc[s][r] = 0.f;

        for (int tt = 0; tt < 66; ++tt) {
            if (tt >= 2) {
                const int jt = tt - 2, j0 = jt * 64, pb = jt & 1;
                const short* vr0 = Vb + (size_t)(w2*64 +  0 + l31) * Nn + j0 + h*8;
                const short* vr1 = Vb + (size_t)(w2*64 + 32 + l31) * Nn + j0 + h*8;
                s16x8 va[4], vb_[4], p0[4], p1[4];
                #pragma unroll
                for (int kj = 0; kj < 4; ++kj) {
                    va[kj]  = *(const s16x8*)(vr0 + kj*16);
                    vb_[kj] = *(const s16x8*)(vr1 + kj*16);
                    p0[kj]  = *(const s16x8*)&Ps[pb][ 0 + l31][kj*16 + h*8];
                    p1[kj]  = *(const s16x8*)&Ps[pb][32 + l31][kj*16 + h*8];
                }
                #pragma unroll
                for (int kj = 0; kj < 4; ++kj) {
                    oacc[0] = MFMA32(va[kj],  p0[kj], oacc[0]);
                    oacc[1] = MFMA32(va[kj],  p1[kj], oacc[1]);
                    oacc[2] = MFMA32(vb_[kj], p0[kj], oacc[2]);
                    oacc[3] = MFMA32(vb_[kj], p1[kj], oacc[3]);
                }
            }
            __syncthreads();
        }
    }

    // ---------------- epilogue: normalize, LDS-transpose, store [n][c]
    if (t < 64) linv[t] = 1.0f / (lpart[0][t] + lpart[1][t]);
    __syncthreads();
    short (*T)[264] = Ks[0];
    if (wid >= 4) {
        const int w2 = wid - 4;
        #pragma unroll
        for (int sub = 0; sub < 4; ++sub) {
            int mc = sub >> 1, nc = sub & 1;
            int ip = nc*32 + l31;
            float rl = linv[ip];
            #pragma unroll
            for (int r = 0; r < 16; ++r) {
                int c = w2*64 + mc*32 + (r & 3) + 8*(r >> 2) + 4*h;
                T[ip][c] = f2bf(oacc[sub][r] * rl);
            }
        }
    }
    __syncthreads();
    short* Ab = ATT + (size_t)b * Nn * Cc;      // [n][c]
    #pragma unroll
    for (int r = 0; r < 8; ++r) {
        int i = r*8 + (t >> 6), c4 = (t & 63) * 4;
        *(s16x4*)&Ab[(size_t)(i0 + i) * Cc + c4] = *(const s16x4*)&T[i][c4];
    }
}

// ---------------------------------------------------------------- proj
__global__ __launch_bounds__(256, 3) void proj_kernel(
    const short* __restrict__ ATT, const float* __restrict__ wp,
    const float* __restrict__ bp, const float* __restrict__ x,
    float* __restrict__ out)
{
    const int nt = blockIdx.x, b = blockIdx.y, oh = blockIdx.z;
    const int n0 = nt * 64;
    const int t = threadIdx.x, lane = t & 63, wid = t >> 6, h = lane >> 5, l31 = lane & 31;
    const short* A = ATT + (size_t)b * Nn * Cc;

    f32x16 acc[2];
    #pragma unroll
    for (int s = 0; s < 2; ++s)
        #pragma unroll
        for (int r = 0; r < 16; ++r) acc[s][r] = 0.f;

    const int og = oh*128 + wid*32;             // this wave's o-group base
    #pragma unroll 4
    for (int kk = 0; kk < 16; ++kk) {
        const float* wr = wp + (size_t)(og + l31) * Cc + kk*16 + h*8;
        float4 lo = *(const float4*)wr, hi = *(const float4*)(wr + 4);
        s16x8 a = { f2bf(lo.x), f2bf(lo.y), f2bf(lo.z), f2bf(lo.w),
                    f2bf(hi.x), f2bf(hi.y), f2bf(hi.z), f2bf(hi.w) };
        s16x8 b0 = *(const s16x8*)&A[(size_t)(n0 +  0 + l31) * Cc + kk*16 + h*8];
        s16x8 b1 = *(const s16x8*)&A[(size_t)(n0 + 32 + l31) * Cc + kk*16 + h*8];
        acc[0] = MFMA32(a, b0, acc[0]);
        acc[1] = MFMA32(a, b1, acc[1]);
    }

    const float* xb = x + (size_t)b * Cc * Nn;
    float* ob = out + (size_t)b * Cc * Nn;
    #pragma unroll
    for (int nc = 0; nc < 2; ++nc) {
        int nloc = nc*32 + l31;
        #pragma unroll
        for (int r = 0; r < 16; ++r) {
            int o = og + (r & 3) + 8*(r >> 2) + 4*h;
            size_t idx = (size_t)o * Nn + n0 + nloc;
            ob[idx] = xb[idx] + acc[nc][r] + bp[o];
        }
    }
}

// ---------------------------------------------------------------- launch
extern "C" void kernel_launch(void* const* d_in, const int* in_sizes, int n_in,
                              void* d_out, int out_size, void* d_ws, size_t ws_size,
                              hipStream_t stream)
{
    const float* x  = (const float*)d_in[0];
    const float* wq = (const float*)d_in[1];
    const float* bq = (const float*)d_in[2];
    const float* wk = (const float*)d_in[3];
    const float* bk = (const float*)d_in[4];
    const float* wv = (const float*)d_in[5];
    const float* bv = (const float*)d_in[6];
    const float* wp = (const float*)d_in[7];
    const float* bp = (const float*)d_in[8];

    const size_t elems = (size_t)4 * Nn * Cc;          // 4.19 M per buffer
    if (ws_size < 4 * elems * sizeof(short)) return;   // 32 MiB scratch
    short* xT = (short*)d_ws;                          // [b][n][c] bf16
    short* QT = xT + elems;                            // [b][n][c] bf16 (= ATT out)
    short* KT = QT + elems;                            // [b][n][c] bf16
    short* V  = KT + elems;                            // [b][c][n] bf16
    short* ATT = QT;                                   // per-tile self-overwrite (block-local)
    (void)in_sizes; (void)n_in; (void)out_size;

    prep_x<<<dim3(64, 4, 4), 256, 0, stream>>>(x, xT);
    qkv_kernel<<<dim3(64, 4, 3), 256, 0, stream>>>(xT, wq, bq, wk, bk, wv, bv, QT, KT, V);
    attn_kernel<<<dim3(256), 512, 0, stream>>>(QT, KT, V, ATT);
    proj_kernel<<<dim3(64, 4, 2), 256, 0, stream>>>(ATT, wp, bp, x, (float*)d_out);
}

// Round 4
// 249.638 us; speedup vs baseline: 1.0666x; 1.0666x over previous
//
#include <hip/hip_runtime.h>
#include <hip/hip_bf16.h>

// NonLocalBlock B=4,C=256,H=W=64 (N=4096) — round 4.
//  wcvt : all 4 weight mats fp32 -> bf16, once (kills per-block cvt flood)
//  qkv  : fused x-transpose-in-LDS + streaming bf16 MFMA (no weight cvt)
//  attn : wave-specialized flash; K via global_load_lds into XOR-swizzled LDS;
//         V double-buffered in registers; no spills (launch_bounds 512,2)
//  proj : streaming bf16 MFMA + residual
// ws = QT(=ATT) | KT | V | Wbf = 25.7 MiB.

typedef __attribute__((ext_vector_type(4))) short s16x4;
typedef __attribute__((ext_vector_type(8))) short s16x8;
typedef __attribute__((ext_vector_type(16))) float f32x16;

#define MFMA32(a, b, c) __builtin_amdgcn_mfma_f32_32x32x16_bf16((a), (b), (c), 0, 0, 0)

constexpr int Cc = 256;
constexpr int Nn = 4096;

__device__ inline short f2bf(float f) {
    unsigned int u = __builtin_bit_cast(unsigned int, f);
    u = (u + 0x7fffu + ((u >> 16) & 1u)) >> 16;   // RNE
    return (short)u;
}

__device__ inline void gl_lds16(const short* g, short* l) {
    // async global->LDS, 16 B/lane; LDS dest = wave-uniform base + lane*16
    __builtin_amdgcn_global_load_lds((const unsigned int*)g, (unsigned int*)l, 16, 0, 0);
}

// 32x32x16 bf16 MFMA layouts (m74/m101-verified C/D; A/B symmetric k-map):
//   A[m=lane&31][k=(lane>>5)*8+j]   B[k=(lane>>5)*8+j][n=lane&31]
//   C/D: col=lane&31, row=(r&3)+8*(r>>2)+4*(lane>>5)

// ---------------------------------------------------------------- wcvt
__global__ __launch_bounds__(256, 4) void wcvt_kernel(
    const float* __restrict__ wq, const float* __restrict__ wk,
    const float* __restrict__ wv, const float* __restrict__ wp,
    short* __restrict__ W)
{
    const int m = blockIdx.y;
    const float* src = (m == 0) ? wq : (m == 1) ? wk : (m == 2) ? wv : wp;
    const int idx = (blockIdx.x * 256 + threadIdx.x) * 8;
    float4 a = *(const float4*)(src + idx);
    float4 b = *(const float4*)(src + idx + 4);
    s16x8 p = { f2bf(a.x), f2bf(a.y), f2bf(a.z), f2bf(a.w),
                f2bf(b.x), f2bf(b.y), f2bf(b.z), f2bf(b.w) };
    *(s16x8*)(W + m * 65536 + idx) = p;
}

// ---------------------------------------------------------------- qkv
// grid (64 n-tiles, 4 b, 3 mat), 256 thr. LDS xT tile 33.8 KB -> 4 blocks/CU.
__global__ __launch_bounds__(256, 4) void qkv_kernel(
    const float* __restrict__ x, const short* __restrict__ W,
    const float* __restrict__ bq, const float* __restrict__ bk,
    const float* __restrict__ bv,
    short* __restrict__ QT, short* __restrict__ KT, short* __restrict__ V)
{
    const int nt = blockIdx.x, b = blockIdx.y, mat = blockIdx.z;
    const int n0 = nt * 64;
    const short* Wm = W + mat * 65536;             // bf16 [o][c]
    const float* bias = (mat == 0) ? bq : (mat == 1) ? bk : bv;
    const int t = threadIdx.x, lane = t & 63, wid = t >> 6, h = lane >> 5, l31 = lane & 31;

    __shared__ alignas(16) short xT[64][264];      // x^T tile [n][c] bf16

    const float* xb = x + (size_t)b * Cc * Nn;
    #pragma unroll
    for (int r = 0; r < 16; ++r) {                 // transpose+cvt 64n x 256c
        int g = r * 256 + t;
        int n = g & 63, cg = g >> 6;
        float f0 = xb[(size_t)(4*cg + 0) * Nn + n0 + n];
        float f1 = xb[(size_t)(4*cg + 1) * Nn + n0 + n];
        float f2 = xb[(size_t)(4*cg + 2) * Nn + n0 + n];
        float f3 = xb[(size_t)(4*cg + 3) * Nn + n0 + n];
        s16x4 p = { f2bf(f0), f2bf(f1), f2bf(f2), f2bf(f3) };
        *(s16x4*)&xT[n][4*cg] = p;
    }
    __syncthreads();

    f32x16 acc[4];
    #pragma unroll
    for (int s = 0; s < 4; ++s)
        #pragma unroll
        for (int r = 0; r < 16; ++r) acc[s][r] = 0.f;

    if (mat < 2) {
        // D[n][o] = sum_c xT[n][c] w[o][c]   (A = xT LDS, B = W rows from L2)
        const int mw = wid & 1, nwb = (wid >> 1) * 4;
        #pragma unroll 4
        for (int kk = 0; kk < 16; ++kk) {
            s16x8 a = *(const s16x8*)&xT[mw*32 + l31][kk*16 + h*8];
            #pragma unroll
            for (int s = 0; s < 4; ++s) {
                s16x8 bb = *(const s16x8*)&Wm[(size_t)((nwb + s)*32 + l31) * Cc + kk*16 + h*8];
                acc[s] = MFMA32(a, bb, acc[s]);
            }
        }
        short* dst = ((mat == 0) ? QT : KT) + (size_t)b * Nn * Cc;
        #pragma unroll
        for (int s = 0; s < 4; ++s) {
            int o = (nwb + s)*32 + l31;
            float bia = bias[o];
            #pragma unroll
            for (int r = 0; r < 16; ++r) {
                int n = mw*32 + (r & 3) + 8*(r >> 2) + 4*h;
                dst[(size_t)(n0 + n) * Cc + o] = f2bf(acc[s][r] + bia);
            }
        }
    } else {
        // D[o][n] = sum_c w[o][c] xT[n][c]   (A = W rows, B = xT LDS)
        #pragma unroll 4
        for (int kk = 0; kk < 16; ++kk) {
            s16x8 a0 = *(const s16x8*)&Wm[(size_t)((wid*2 + 0)*32 + l31) * Cc + kk*16 + h*8];
            s16x8 a1 = *(const s16x8*)&Wm[(size_t)((wid*2 + 1)*32 + l31) * Cc + kk*16 + h*8];
            s16x8 b0 = *(const s16x8*)&xT[ 0 + l31][kk*16 + h*8];
            s16x8 b1 = *(const s16x8*)&xT[32 + l31][kk*16 + h*8];
            acc[0] = MFMA32(a0, b0, acc[0]);
            acc[1] = MFMA32(a0, b1, acc[1]);
            acc[2] = MFMA32(a1, b0, acc[2]);
            acc[3] = MFMA32(a1, b1, acc[3]);
        }
        short* dst = V + (size_t)b * Cc * Nn;
        #pragma unroll
        for (int sub = 0; sub < 4; ++sub) {
            int mc = sub >> 1, nc = sub & 1;
            int nloc = nc*32 + l31;
            #pragma unroll
            for (int r = 0; r < 16; ++r) {
                int o = (wid*2 + mc)*32 + (r & 3) + 8*(r >> 2) + 4*h;
                dst[(size_t)o * Nn + n0 + nloc] = f2bf(acc[sub][r] + bias[o]);
            }
        }
    }
}

// ---------------------------------------------------------------- attn
// 512 thr: waves 0-3 produce P (QK+exp), waves 4-7 consume (PV).
// Ks: unpadded [2][64][256], XOR-swizzled granules (conflict-free b128),
// filled by global_load_lds.  LDS total ~84.7 KB, grid 256 -> 1 block/CU.
__global__ __launch_bounds__(512, 2) void attn_kernel(
    const short* __restrict__ QTg, const short* __restrict__ KTg,
    const short* __restrict__ Vg, short* __restrict__ ATT)
{
    const int bid = blockIdx.x;
    const int b  = (bid & 7) >> 1;              // batch per XCD pair
    const int qt = ((bid >> 3) << 1) | (bid & 1);
    const int i0 = qt * 64;

    const int t = threadIdx.x, lane = t & 63, wid = t >> 6, h = lane >> 5, l31 = lane & 31;

    __shared__ alignas(16) short Ks[2][64][256]; // swizzled: slot g holds granule g^ (row&31)
    __shared__ alignas(16) short Ps[2][64][72];
    __shared__ float lpart[2][64];
    __shared__ float linv[64];
    short* KsF = &Ks[0][0][0];

    const short* Qb = QTg + (size_t)b * Nn * Cc;
    const short* Kb = KTg + (size_t)b * Nn * Cc;
    const short* Vb = Vg  + (size_t)b * Cc * Nn;

    const float SC = 0.09016844005f;            // C^-0.5 * log2(e)
    f32x16 oacc[4];

    if (wid < 4) {
        // ---------------- producer: S^T = K Q^T, exp, P
        const int w4 = wid, mj = w4 >> 1, ni = w4 & 1;

        s16x8 qf[16];
        {
            const short* qrow = Qb + (size_t)(i0 + ni*32 + l31) * Cc + h*8;
            #pragma unroll
            for (int kc = 0; kc < 16; ++kc) qf[kc] = *(const s16x8*)(qrow + kc*16);
        }
        float lacc = 0.f;
        const int rl = mj*32 + l31;             // A-frag row; (rl&31)==l31

        for (int tt = 0; tt < 66; ++tt) {
            if (tt < 64) {                       // stage K tile tt (async DMA)
                const int kb = tt & 1;
                #pragma unroll
                for (int it = 0; it < 8; ++it) {
                    int r = (w4*8 + it)*2 + (lane >> 5);
                    int g = l31 ^ (r & 31);
                    const short* gp = Kb + (size_t)(tt*64 + r) * Cc + g*8;
                    short* lp = KsF + kb*16384 + (w4*8 + it)*512;  // wave-uniform
                    gl_lds16(gp, lp);
                }
            }
            if (tt >= 1 && tt < 65) {
                const int jt = tt - 1, kb = jt & 1;
                const short* abase = KsF + kb*16384 + rl*256;
                f32x16 s0, s1;
                #pragma unroll
                for (int r = 0; r < 16; ++r) { s0[r] = 0.f; s1[r] = 0.f; }
                #pragma unroll
                for (int kc = 0; kc < 8; ++kc) {
                    s16x8 a0 = *(const s16x8*)(abase + (((kc*4 + 0 + h) ^ l31) << 3));
                    s16x8 a1 = *(const s16x8*)(abase + (((kc*4 + 2 + h) ^ l31) << 3));
                    s0 = MFMA32(a0, qf[2*kc + 0], s0);
                    s1 = MFMA32(a1, qf[2*kc + 1], s1);
                }
                float ps[16], lsum = 0.f;
                #pragma unroll
                for (int r = 0; r < 16; ++r) {
                    float e = exp2f((s0[r] + s1[r]) * SC);
                    ps[r] = e; lsum += e;
                }
                lsum += __shfl_xor(lsum, 32);
                lacc += lsum;
                const int ip = ni*32 + l31;
                #pragma unroll
                for (int g = 0; g < 4; ++g) {
                    s16x4 pk = { f2bf(ps[4*g+0]), f2bf(ps[4*g+1]),
                                 f2bf(ps[4*g+2]), f2bf(ps[4*g+3]) };
                    *(s16x4*)&Ps[kb][ip][mj*32 + g*8 + 4*h] = pk;
                }
            }
            __syncthreads();
        }
        if (h == 0) lpart[mj][ni*32 + l31] = lacc;
    } else {
        // ---------------- consumer: O^T[c][i] += V[c][j] P[i][j]
        const int w2 = wid - 4;
        #pragma unroll
        for (int s = 0; s < 4; ++s)
            #pragma unroll
            for (int r = 0; r < 16; ++r) oacc[s][r] = 0.f;

        s16x8 vA[8], vB[8];
        const short* vb0 = Vb + (size_t)(w2*64 +  0 + l31) * Nn + h*8;
        const short* vb1 = Vb + (size_t)(w2*64 + 32 + l31) * Nn + h*8;

        for (int tp = 0; tp < 33; ++tp) {
            const int t0 = tp*2, t1 = t0 + 1;
            // even step t0: issue tile t0-1 -> vA ; consume tile t0-2 from vB
            if (t0 >= 1 && t0 <= 64) {
                const int j0 = (t0 - 1) * 64;
                #pragma unroll
                for (int kj = 0; kj < 4; ++kj) {
                    vA[kj]   = *(const s16x8*)(vb0 + j0 + kj*16);
                    vA[4+kj] = *(const s16x8*)(vb1 + j0 + kj*16);
                }
            }
            if (t0 >= 2) {
                const int pb = (t0 - 2) & 1;
                s16x8 p0[4], p1[4];
                #pragma unroll
                for (int kj = 0; kj < 4; ++kj) {
                    p0[kj] = *(const s16x8*)&Ps[pb][ 0 + l31][kj*16 + h*8];
                    p1[kj] = *(const s16x8*)&Ps[pb][32 + l31][kj*16 + h*8];
                }
                #pragma unroll
                for (int kj = 0; kj < 4; ++kj) {
                    oacc[0] = MFMA32(vB[kj],   p0[kj], oacc[0]);
                    oacc[1] = MFMA32(vB[kj],   p1[kj], oacc[1]);
                    oacc[2] = MFMA32(vB[4+kj], p0[kj], oacc[2]);
                    oacc[3] = MFMA32(vB[4+kj], p1[kj], oacc[3]);
                }
            }
            __syncthreads();
            // odd step t1: issue tile t1-1 -> vB ; consume tile t1-2 from vA
            if (t1 <= 64) {
                const int j0 = (t1 - 1) * 64;
                #pragma unroll
                for (int kj = 0; kj < 4; ++kj) {
                    vB[kj]   = *(const s16x8*)(vb0 + j0 + kj*16);
                    vB[4+kj] = *(const s16x8*)(vb1 + j0 + kj*16);
                }
            }
            if (t1 >= 2) {
                const int pb = (t1 - 2) & 1;
                s16x8 p0[4], p1[4];
                #pragma unroll
                for (int kj = 0; kj < 4; ++kj) {
                    p0[kj] = *(const s16x8*)&Ps[pb][ 0 + l31][kj*16 + h*8];
                    p1[kj] = *(const s16x8*)&Ps[pb][32 + l31][kj*16 + h*8];
                }
                #pragma unroll
                for (int kj = 0; kj < 4; ++kj) {
                    oacc[0] = MFMA32(vA[kj],   p0[kj], oacc[0]);
                    oacc[1] = MFMA32(vA[kj],   p1[kj], oacc[1]);
                    oacc[2] = MFMA32(vA[4+kj], p0[kj], oacc[2]);
                    oacc[3] = MFMA32(vA[4+kj], p1[kj], oacc[3]);
                }
            }
            __syncthreads();
        }
    }

    // ---------------- epilogue: normalize, LDS-transpose, store [n][c]
    __syncthreads();
    if (t < 64) linv[t] = 1.0f / (lpart[0][t] + lpart[1][t]);
    __syncthreads();
    short (*T)[264] = (short(*)[264])KsF;       // scratch over Ks
    if (wid >= 4) {
        const int w2 = wid - 4;
        #pragma unroll
        for (int sub = 0; sub < 4; ++sub) {
            int mc = sub >> 1, nc = sub & 1;
            int ip = nc*32 + l31;
            float rl2 = linv[ip];
            #pragma unroll
            for (int r = 0; r < 16; ++r) {
                int c = w2*64 + mc*32 + (r & 3) + 8*(r >> 2) + 4*h;
                T[ip][c] = f2bf(oacc[sub][r] * rl2);
            }
        }
    }
    __syncthreads();
    short* Ab = ATT + (size_t)b * Nn * Cc;      // [n][c]
    #pragma unroll
    for (int r = 0; r < 8; ++r) {
        int i = r*8 + (t >> 6), c4 = (t & 63) * 4;
        *(s16x4*)&Ab[(size_t)(i0 + i) * Cc + c4] = *(const s16x4*)&T[i][c4];
    }
}

// ---------------------------------------------------------------- proj
__global__ __launch_bounds__(256, 4) void proj_kernel(
    const short* __restrict__ ATT, const short* __restrict__ W,
    const float* __restrict__ bp, const float* __restrict__ x,
    float* __restrict__ out)
{
    const int nt = blockIdx.x, b = blockIdx.y, oh = blockIdx.z;
    const int n0 = nt * 64;
    const int t = threadIdx.x, lane = t & 63, wid = t >> 6, h = lane >> 5, l31 = lane & 31;
    const short* A = ATT + (size_t)b * Nn * Cc;
    const short* Wp = W + 3 * 65536;

    f32x16 acc[2];
    #pragma unroll
    for (int s = 0; s < 2; ++s)
        #pragma unroll
        for (int r = 0; r < 16; ++r) acc[s][r] = 0.f;

    const int og = oh*128 + wid*32;
    #pragma unroll 4
    for (int kk = 0; kk < 16; ++kk) {
        s16x8 a  = *(const s16x8*)&Wp[(size_t)(og + l31) * Cc + kk*16 + h*8];
        s16x8 b0 = *(const s16x8*)&A[(size_t)(n0 +  0 + l31) * Cc + kk*16 + h*8];
        s16x8 b1 = *(const s16x8*)&A[(size_t)(n0 + 32 + l31) * Cc + kk*16 + h*8];
        acc[0] = MFMA32(a, b0, acc[0]);
        acc[1] = MFMA32(a, b1, acc[1]);
    }

    const float* xb = x + (size_t)b * Cc * Nn;
    float* ob = out + (size_t)b * Cc * Nn;
    #pragma unroll
    for (int nc = 0; nc < 2; ++nc) {
        int nloc = nc*32 + l31;
        #pragma unroll
        for (int r = 0; r < 16; ++r) {
            int o = og + (r & 3) + 8*(r >> 2) + 4*h;
            size_t idx = (size_t)o * Nn + n0 + nloc;
            ob[idx] = xb[idx] + acc[nc][r] + bp[o];
        }
    }
}

// ---------------------------------------------------------------- launch
extern "C" void kernel_launch(void* const* d_in, const int* in_sizes, int n_in,
                              void* d_out, int out_size, void* d_ws, size_t ws_size,
                              hipStream_t stream)
{
    const float* x  = (const float*)d_in[0];
    const float* wq = (const float*)d_in[1];
    const float* bq = (const float*)d_in[2];
    const float* wk = (const float*)d_in[3];
    const float* bk = (const float*)d_in[4];
    const float* wv = (const float*)d_in[5];
    const float* bv = (const float*)d_in[6];
    const float* wp = (const float*)d_in[7];
    const float* bp = (const float*)d_in[8];

    const size_t elems = (size_t)4 * Nn * Cc;                 // 4.19 M / buffer
    const size_t need  = (3 * elems + 4 * 65536) * sizeof(short);  // 25.7 MiB
    if (ws_size < need) return;
    short* QT  = (short*)d_ws;                 // [b][n][c] bf16  (= ATT out)
    short* KT  = QT + elems;                   // [b][n][c] bf16
    short* V   = KT + elems;                   // [b][c][n] bf16
    short* Wbf = V + elems;                    // 4 x [o][c] bf16
    short* ATT = QT;                           // block-local self-overwrite
    (void)in_sizes; (void)n_in; (void)out_size;

    wcvt_kernel<<<dim3(32, 4), 256, 0, stream>>>(wq, wk, wv, wp, Wbf);
    qkv_kernel<<<dim3(64, 4, 3), 256, 0, stream>>>(x, Wbf, bq, bk, bv, QT, KT, V);
    attn_kernel<<<dim3(256), 512, 0, stream>>>(QT, KT, V, ATT);
    proj_kernel<<<dim3(64, 4, 2), 256, 0, stream>>>(ATT, Wbf, bp, x, (float*)d_out);
}